// Round 6
// baseline (774.710 us; speedup 1.0000x reference)
//
#include <hip/hip_runtime.h>

#define N_NODES 110000
#define NUM_USER 60000
#define MPAD 110016        // N_NODES padded to 64-row GEMM tiles
#define ZROW N_NODES       // dedicated all-zero row in Tp (rows N..MPAD-1 zeroed once)
#define BSHIFT 9           // bucket = dst >> 9  (512 nodes per bucket)
#define NBUCK 256
#define NPB 512            // nodes per bucket
#define EPB 8192           // edges per block in hist/bin
#define CAP 9216           // per-bucket edge capacity in csr_k LDS

typedef __attribute__((ext_vector_type(8))) __bf16 bf16x8;
typedef __attribute__((ext_vector_type(4))) float f32x4;
typedef __attribute__((ext_vector_type(4))) unsigned int uint4v;

union UB { uint4v u; bf16x8 b; };

__device__ __forceinline__ unsigned short f2b(float f) {   // f32 -> bf16 RNE
    unsigned int u = __float_as_uint(f);
    unsigned int r = (u + 0x7FFFu + ((u >> 16) & 1u)) >> 16;
    return (unsigned short)r;
}
__device__ __forceinline__ float b2f(unsigned short h) {
    return __uint_as_float(((unsigned int)h) << 16);
}

// ---------------- bucket-sort CSR build ----------------

__global__ __launch_bounds__(256) void hist_k(const int* __restrict__ dst, int* __restrict__ tbl, int E) {
    __shared__ int h[NBUCK];
    int tid = threadIdx.x, b = blockIdx.x;
    h[tid] = 0;
    __syncthreads();
    int base = b * EPB, end = min(base + EPB, E);
    for (int i = base + tid * 4; i + 3 < end; i += 1024) {
        int4 d = *(const int4*)&dst[i];
        atomicAdd(&h[d.x >> BSHIFT], 1); atomicAdd(&h[d.y >> BSHIFT], 1);
        atomicAdd(&h[d.z >> BSHIFT], 1); atomicAdd(&h[d.w >> BSHIFT], 1);
    }
    __syncthreads();
    tbl[b * NBUCK + tid] = h[tid];
}

__global__ __launch_bounds__(256) void scanb_k(int* __restrict__ tbl, int* __restrict__ bbase,
                                               int* __restrict__ bcnt, int nblocks) {
    __shared__ int sh[NBUCK];
    int t = threadIdx.x;
    int s = 0;
    for (int blk = 0; blk < nblocks; blk++) {
        int v = tbl[blk * NBUCK + t];
        tbl[blk * NBUCK + t] = s;
        s += v;
    }
    bcnt[t] = s;
    sh[t] = s;
    __syncthreads();
    for (int o = 1; o < NBUCK; o <<= 1) {
        int v = (t >= o) ? sh[t - o] : 0;
        __syncthreads();
        sh[t] += v;
        __syncthreads();
    }
    bbase[t] = sh[t] - s;   // exclusive
}

__global__ __launch_bounds__(256) void bin_k(const int* __restrict__ src, const int* __restrict__ dst,
        const int* __restrict__ tbl, const int* __restrict__ bbase,
        unsigned int* __restrict__ stg, int E) {
    __shared__ int lcur[NBUCK];
    int tid = threadIdx.x, b = blockIdx.x;
    lcur[tid] = bbase[tid] + tbl[b * NBUCK + tid];
    __syncthreads();
    int base = b * EPB, end = min(base + EPB, E);
    for (int i = base + tid * 4; i + 3 < end; i += 1024) {
        int4 s = *(const int4*)&src[i];
        int4 d = *(const int4*)&dst[i];
        int p;
        p = atomicAdd(&lcur[d.x >> BSHIFT], 1); stg[p] = (unsigned)s.x | ((unsigned)(d.x & (NPB - 1)) << 17);
        p = atomicAdd(&lcur[d.y >> BSHIFT], 1); stg[p] = (unsigned)s.y | ((unsigned)(d.y & (NPB - 1)) << 17);
        p = atomicAdd(&lcur[d.z >> BSHIFT], 1); stg[p] = (unsigned)s.z | ((unsigned)(d.z & (NPB - 1)) << 17);
        p = atomicAdd(&lcur[d.w >> BSHIFT], 1); stg[p] = (unsigned)s.w | ((unsigned)(d.w & (NPB - 1)) << 17);
    }
}

__global__ __launch_bounds__(256) void csr_k(const unsigned int* __restrict__ stg,
        const int* __restrict__ bbase, const int* __restrict__ bcnt,
        int* __restrict__ deg, float* __restrict__ dinv, int* __restrict__ off,
        int* __restrict__ idxb, int N) {
    __shared__ int ldeg[NPB];
    __shared__ int lcur[NPB];
    __shared__ int shp[256];
    __shared__ unsigned int lidx[CAP];
    int tid = threadIdx.x, b = blockIdx.x;
    int node0 = b * NPB;
    int base = bbase[b], cnt = bcnt[b];
    ldeg[tid] = 0; ldeg[tid + 256] = 0;
    __syncthreads();
    for (int i = tid; i < cnt; i += 256)
        atomicAdd(&ldeg[stg[base + i] >> 17], 1);
    __syncthreads();
    int a0 = ldeg[2 * tid], a1 = ldeg[2 * tid + 1];
    shp[tid] = a0 + a1;
    __syncthreads();
    for (int o = 1; o < 256; o <<= 1) {
        int v = (tid >= o) ? shp[tid - o] : 0;
        __syncthreads();
        shp[tid] += v;
        __syncthreads();
    }
    int excl = shp[tid] - a0 - a1;
    lcur[2 * tid] = excl;
    lcur[2 * tid + 1] = excl + a0;
    int n0 = node0 + 2 * tid;
    if (n0 < N)     { deg[n0] = a0;     dinv[n0] = rsqrtf(a0 + 1.f);     off[n0] = base + excl; }
    if (n0 + 1 < N) { deg[n0 + 1] = a1; dinv[n0 + 1] = rsqrtf(a1 + 1.f); off[n0 + 1] = base + excl + a0; }
    __syncthreads();
    for (int i = tid; i < cnt; i += 256) {
        unsigned e = stg[base + i];
        int p = atomicAdd(&lcur[e >> 17], 1);
        if (p < CAP) lidx[p] = e & 0x1FFFFu;
    }
    __syncthreads();
    for (int i = tid; i < cnt; i += 256)
        idxb[base + i] = (int)lidx[i];
}

// ---------------- weights: W (128x128, [k][n]) -> transposed bf16 hi/lo ([n][k]) ----------------

__global__ __launch_bounds__(256) void convw_k(const float* __restrict__ W,
        ushort* __restrict__ hi, ushort* __restrict__ lo) {
    int i = blockIdx.x * blockDim.x + threadIdx.x;   // 16384 total
    int k = i >> 7, n = i & 127;
    float w = W[i];
    ushort h = f2b(w);
    hi[(n << 7) | k] = h;
    lo[(n << 7) | k] = f2b(w - b2f(h));
}

// zero Tp rows N..MPAD-1 once (ZROW padding rows; mm_k never writes them)
__global__ void zrow_k(ushort* __restrict__ Tp) {
    int i = blockIdx.x * blockDim.x + threadIdx.x;   // (MPAD-N_NODES)*128 = 2048
    Tp[(size_t)N_NODES * 128 + i] = 0;
}

// ---------------- GEMM: T'(bf16, Mx128) = dinv[row] * (A @ W), split-bf16 MFMA ----------------

template<bool F32A>
__global__ __launch_bounds__(256) void mm_k(const float* __restrict__ Xf,
        const ushort* __restrict__ Xhi, const ushort* __restrict__ Xlo,
        const ushort* __restrict__ Whi, const ushort* __restrict__ Wlo,   // [n][k]
        const float* __restrict__ dinv, ushort* __restrict__ Tp, int M) {
    int wid = threadIdx.x >> 6, lane = threadIdx.x & 63;
    int row0 = blockIdx.x * 64 + wid * 16;
    int l15 = lane & 15;
    int rA = row0 + l15;
    int kg = (lane >> 4) * 8;
    f32x4 acc[8] = {};
    #pragma unroll
    for (int g = 0; g < 4; g++) {
        int k0 = g * 32 + kg;
        UB ahi, alo;
        if (F32A) {
            float4 f0 = make_float4(0.f, 0.f, 0.f, 0.f), f1 = f0;
            if (rA < M) {
                f0 = *(const float4*)&Xf[(size_t)rA * 128 + k0];
                f1 = *(const float4*)&Xf[(size_t)rA * 128 + k0 + 4];
            }
            float f[8] = {f0.x, f0.y, f0.z, f0.w, f1.x, f1.y, f1.z, f1.w};
            ushort h[8], l[8];
            #pragma unroll
            for (int j = 0; j < 8; j++) { h[j] = f2b(f[j]); l[j] = f2b(f[j] - b2f(h[j])); }
            ahi.u = uint4v{(uint)h[0] | ((uint)h[1] << 16), (uint)h[2] | ((uint)h[3] << 16),
                           (uint)h[4] | ((uint)h[5] << 16), (uint)h[6] | ((uint)h[7] << 16)};
            alo.u = uint4v{(uint)l[0] | ((uint)l[1] << 16), (uint)l[2] | ((uint)l[3] << 16),
                           (uint)l[4] | ((uint)l[5] << 16), (uint)l[6] | ((uint)l[7] << 16)};
        } else {
            ahi.u = *(const uint4v*)&Xhi[(size_t)rA * 128 + k0];
            alo.u = *(const uint4v*)&Xlo[(size_t)rA * 128 + k0];
        }
        #pragma unroll
        for (int n = 0; n < 8; n++) {
            UB bhi, blo;
            bhi.u = *(const uint4v*)&Whi[(n * 16 + l15) * 128 + k0];
            blo.u = *(const uint4v*)&Wlo[(n * 16 + l15) * 128 + k0];
            acc[n] = __builtin_amdgcn_mfma_f32_16x16x32_bf16(ahi.b, bhi.b, acc[n], 0, 0, 0);
            acc[n] = __builtin_amdgcn_mfma_f32_16x16x32_bf16(ahi.b, blo.b, acc[n], 0, 0, 0);
            acc[n] = __builtin_amdgcn_mfma_f32_16x16x32_bf16(alo.b, bhi.b, acc[n], 0, 0, 0);
        }
    }
    int rbase = row0 + (lane >> 4) * 4;
    #pragma unroll
    for (int r = 0; r < 4; r++) {
        int row = rbase + r;
        if (row < M) {
            float dv = dinv[row];
            #pragma unroll
            for (int n = 0; n < 8; n++)
                Tp[(size_t)row * 128 + n * 16 + l15] = f2b(dv * acc[n][r]);
        }
    }
}

// ---------------- aggregate + fused per-node head dots ----------------
// One wave per dst node. 16 lanes per edge (4 edges in flight); lane holds 16 B (8 dims).
// out[d] = relu(b + dinv[d]*(T'[d] + sum T'[src])), hi/lo split; nd[d*4+g] = head dot g.

__global__ __launch_bounds__(256) void aggregate_k(const ushort* __restrict__ Tp,
        const int* __restrict__ idxb, const int* __restrict__ off, const int* __restrict__ deg,
        const float* __restrict__ dinv, const float* __restrict__ bias,
        const float* __restrict__ Wp, const float* __restrict__ Wdu, const float* __restrict__ Wdi,
        int loff,   // 0 for layer 1, 128 for layer 2
        float* __restrict__ nd,
        ushort* __restrict__ ohi, ushort* __restrict__ olo, int N) {
    int w = threadIdx.x >> 6, lane = threadIdx.x & 63;
    int d = blockIdx.x * 4 + w;
    int grp = lane >> 4, li = lane & 15;
    int db = li * 8;   // first dim this lane owns
    if (d >= N) {   // pad rows for GEMM tiles: keep zeroed
        if (grp == 0) *(uint4*)&ohi[(size_t)d * 128 + db] = make_uint4(0, 0, 0, 0);
        if (grp == 1) *(uint4*)&olo[(size_t)d * 128 + db] = make_uint4(0, 0, 0, 0);
        return;
    }
    float aE0 = 0.f, aO0 = 0.f, aE1 = 0.f, aO1 = 0.f;
    float aE2 = 0.f, aO2 = 0.f, aE3 = 0.f, aO3 = 0.f;
    int o = off[d];
    int cnt = deg[d] + 1;   // position 0 = self
    const unsigned char* tpb = (const unsigned char*)Tp;
    unsigned int laneoff = (unsigned int)(li << 4);
    for (int c = 0; c < cnt; c += 64) {
        int p = c + lane;
        int id = ZROW;
        if (p < cnt) id = (p == 0) ? d : idxb[o + p - 1];
        int m = min(64, cnt - c);
        #pragma unroll 4
        for (int jj = 0; jj * 4 < m; jj++) {
            int s = __shfl(id, jj * 4 + grp);
            uint4 u = *(const uint4*)(tpb + (((unsigned int)s << 8) | laneoff));
            aO0 += __uint_as_float(u.x & 0xFFFF0000u); aE0 += __uint_as_float(u.x << 16);
            aO1 += __uint_as_float(u.y & 0xFFFF0000u); aE1 += __uint_as_float(u.y << 16);
            aO2 += __uint_as_float(u.z & 0xFFFF0000u); aE2 += __uint_as_float(u.z << 16);
            aO3 += __uint_as_float(u.w & 0xFFFF0000u); aE3 += __uint_as_float(u.w << 16);
        }
    }
    // cross-group reduce: all 4 groups end with identical sums for dims db..db+7
    #define RED2(x) { x += __shfl_xor(x, 16); x += __shfl_xor(x, 32); }
    RED2(aE0) RED2(aO0) RED2(aE1) RED2(aO1)
    RED2(aE2) RED2(aO2) RED2(aE3) RED2(aO3)
    #undef RED2
    float di = dinv[d];
    float4 b0 = *(const float4*)&bias[db];
    float4 b1 = *(const float4*)&bias[db + 4];
    float f0 = fmaxf(di * aE0 + b0.x, 0.f);
    float f1 = fmaxf(di * aO0 + b0.y, 0.f);
    float f2 = fmaxf(di * aE1 + b0.z, 0.f);
    float f3 = fmaxf(di * aO1 + b0.w, 0.f);
    float f4 = fmaxf(di * aE2 + b1.x, 0.f);
    float f5 = fmaxf(di * aO2 + b1.y, 0.f);
    float f6 = fmaxf(di * aE3 + b1.z, 0.f);
    float f7 = fmaxf(di * aO3 + b1.w, 0.f);
    if (grp < 2) {
        ushort h0 = f2b(f0), h1 = f2b(f1), h2 = f2b(f2), h3 = f2b(f3);
        ushort h4 = f2b(f4), h5 = f2b(f5), h6 = f2b(f6), h7 = f2b(f7);
        if (grp == 0) {
            uint4 hv = make_uint4((uint)h0 | ((uint)h1 << 16), (uint)h2 | ((uint)h3 << 16),
                                  (uint)h4 | ((uint)h5 << 16), (uint)h6 | ((uint)h7 << 16));
            *(uint4*)&ohi[(size_t)d * 128 + db] = hv;
        } else {
            ushort l0 = f2b(f0 - b2f(h0)), l1 = f2b(f1 - b2f(h1));
            ushort l2 = f2b(f2 - b2f(h2)), l3 = f2b(f3 - b2f(h3));
            ushort l4 = f2b(f4 - b2f(h4)), l5 = f2b(f5 - b2f(h5));
            ushort l6 = f2b(f6 - b2f(h6)), l7 = f2b(f7 - b2f(h7));
            uint4 lv = make_uint4((uint)l0 | ((uint)l1 << 16), (uint)l2 | ((uint)l3 << 16),
                                  (uint)l4 | ((uint)l5 << 16), (uint)l6 | ((uint)l7 << 16));
            *(uint4*)&olo[(size_t)d * 128 + db] = lv;
        }
    }
    // head dots: group g computes dot g over the full 128 dims
    const float* wsel = (grp == 0) ? Wp + loff : (grp == 1) ? Wp + 256 + loff
                      : (grp == 2) ? Wdu + loff : Wdi + loff;
    float4 w0 = *(const float4*)&wsel[db];
    float4 w1 = *(const float4*)&wsel[db + 4];
    float dt = f0 * w0.x + f1 * w0.y + f2 * w0.z + f3 * w0.w
             + f4 * w1.x + f5 * w1.y + f6 * w1.z + f7 * w1.w;
    dt += __shfl_xor(dt, 1); dt += __shfl_xor(dt, 2);
    dt += __shfl_xor(dt, 4); dt += __shfl_xor(dt, 8);
    if (li == 0) nd[(size_t)d * 4 + grp] = dt;
}

// ---------------- loss: per-sample scalar gathers from node-dot tables ----------------

__device__ __forceinline__ float sp100(float z) {   // min(softplus(z),100)
    float sp = (z > 0.f) ? (z + log1pf(expf(-z))) : log1pf(expf(z));
    return fminf(sp, 100.f);
}
__device__ __forceinline__ float wred64(float x) {
    #pragma unroll
    for (int o = 32; o > 0; o >>= 1) x += __shfl_xor(x, o);
    return x;
}

__global__ __launch_bounds__(256) void loss_k(const float* __restrict__ nd1, const float* __restrict__ nd2,
        const int* __restrict__ user, const int* __restrict__ item, const int* __restrict__ labels,
        const float* __restrict__ bp, const float* __restrict__ bdu, const float* __restrict__ bdi,
        float* __restrict__ acc, int is_target, int B) {
    __shared__ float sh[3][4];
    int gtid = blockIdx.x * blockDim.x + threadIdx.x;
    int nth = gridDim.x * blockDim.x;
    float bpv = bp[0], bduv = bdu[0], bdiv = bdi[0];
    float lp = 0.f, lu = 0.f, li = 0.f;
    for (int s = gtid; s < B; s += nth) {
        int u = user[s];
        int it = item[s] + NUM_USER;
        float4 a = *(const float4*)&nd1[(size_t)u * 4];
        float4 b = *(const float4*)&nd2[(size_t)u * 4];
        float4 c = *(const float4*)&nd1[(size_t)it * 4];
        float4 dd = *(const float4*)&nd2[(size_t)it * 4];
        float zp = a.x + b.x + c.y + dd.y + bpv;
        float zu = a.z + b.z + bduv;
        float zi = c.w + dd.w + bdiv;
        lp += labels[s] ? sp100(-zp) : sp100(zp);
        lu += is_target ? sp100(-zu) : sp100(zu);
        li += is_target ? sp100(-zi) : sp100(zi);
    }
    lp = wred64(lp); lu = wred64(lu); li = wred64(li);
    int lane = threadIdx.x & 63, w = threadIdx.x >> 6;
    if (lane == 0) { sh[0][w] = lp; sh[1][w] = lu; sh[2][w] = li; }
    __syncthreads();
    if (threadIdx.x == 0) {
        float s0 = 0.f, s1 = 0.f, s2 = 0.f;
        for (int j = 0; j < 4; j++) { s0 += sh[0][j]; s1 += sh[1][j]; s2 += sh[2][j]; }
        atomicAdd(&acc[is_target ? 1 : 0], s0);
        atomicAdd(&acc[2], s1);
        atomicAdd(&acc[3], s2);
    }
}

__global__ void fin_k(const float* __restrict__ acc, float* __restrict__ out, int B) {
    float invB = 1.f / (float)B;
    out[0] = acc[0] * invB + acc[1] * invB + 0.1f * ((acc[2] + acc[3]) * (0.5f * invB));
}

// ---------------- orchestration ----------------

extern "C" void kernel_launch(void* const* d_in, const int* in_sizes, int n_in,
                              void* d_out, int out_size, void* d_ws, size_t ws_size,
                              hipStream_t stream) {
    const float* feats[2] = {(const float*)d_in[0], (const float*)d_in[1]};
    const int* adj[2]    = {(const int*)d_in[2], (const int*)d_in[3]};
    const int* user[2]   = {(const int*)d_in[4], (const int*)d_in[7]};
    const int* item[2]   = {(const int*)d_in[5], (const int*)d_in[8]};
    const int* labels[2] = {(const int*)d_in[6], (const int*)d_in[9]};
    const float* Wl[2] = {(const float*)d_in[10], (const float*)d_in[12]};
    const float* bl[2] = {(const float*)d_in[11], (const float*)d_in[13]};
    const float* Wp  = (const float*)d_in[14];
    const float* bp  = (const float*)d_in[15];
    const float* Wdu = (const float*)d_in[16];
    const float* bdu = (const float*)d_in[17];
    const float* Wdi = (const float*)d_in[18];
    const float* bdi = (const float*)d_in[19];

    const int E = in_sizes[2] / 2;
    const int B = in_sizes[4];
    const int N = N_NODES;

    char* w = (char*)d_ws;
    ushort* Tp   = (ushort*)w; w += (size_t)MPAD * 128 * 2;
    ushort* Fhi  = (ushort*)w; w += (size_t)MPAD * 128 * 2;
    ushort* Flo  = (ushort*)w; w += (size_t)MPAD * 128 * 2;
    ushort* W1h  = (ushort*)w; w += 16384 * 2;
    ushort* W1l  = (ushort*)w; w += 16384 * 2;
    ushort* W2h  = (ushort*)w; w += 16384 * 2;
    ushort* W2l  = (ushort*)w; w += 16384 * 2;
    float* nd1  = (float*)w; w += (size_t)N * 16;
    float* nd2  = (float*)w; w += (size_t)N * 16;
    int*   deg  = (int*)w;   w += (size_t)N * 4;
    float* dinv = (float*)w; w += (size_t)N * 4;
    int*   off  = (int*)w;   w += (size_t)N * 4;
    int*   idxb = (int*)w;   w += (size_t)E * 4;
    unsigned int* stg = (unsigned int*)w; w += (size_t)E * 4;
    int*   tbl  = (int*)w;   w += (size_t)512 * NBUCK * 4;
    int*   bbase = (int*)w;  w += NBUCK * 4;
    int*   bcnt  = (int*)w;  w += NBUCK * 4;
    float* acc  = (float*)w; w += 64;

    hipMemsetAsync(acc, 0, 64, stream);
    convw_k<<<64, 256, 0, stream>>>(Wl[0], W1h, W1l);
    convw_k<<<64, 256, 0, stream>>>(Wl[1], W2h, W2l);
    zrow_k<<<8, 256, 0, stream>>>(Tp);

    int nbE = (E + EPB - 1) / EPB;
    int nbB = (N + NPB - 1) / NPB;
    int gMM = MPAD / 64, gAG = MPAD / 4;
    for (int dom = 0; dom < 2; dom++) {
        const int* srcp = adj[dom];
        const int* dstp = adj[dom] + E;

        hist_k<<<nbE, 256, 0, stream>>>(dstp, tbl, E);
        scanb_k<<<1, 256, 0, stream>>>(tbl, bbase, bcnt, nbE);
        bin_k<<<nbE, 256, 0, stream>>>(srcp, dstp, tbl, bbase, stg, E);
        csr_k<<<nbB, 256, 0, stream>>>(stg, bbase, bcnt, deg, dinv, off, idxb, N);

        // layer 1 (f32 input feats, split in-register)
        mm_k<true><<<gMM, 256, 0, stream>>>(feats[dom], nullptr, nullptr, W1h, W1l, dinv, Tp, N);
        aggregate_k<<<gAG, 256, 0, stream>>>(Tp, idxb, off, deg, dinv, bl[0],
                                             Wp, Wdu, Wdi, 0, nd1, Fhi, Flo, N);

        // layer 2 (bf16 hi/lo input)
        mm_k<false><<<gMM, 256, 0, stream>>>(nullptr, Fhi, Flo, W2h, W2l, dinv, Tp, N);
        aggregate_k<<<gAG, 256, 0, stream>>>(Tp, idxb, off, deg, dinv, bl[1],
                                             Wp, Wdu, Wdi, 128, nd2, Fhi, Flo, N);

        loss_k<<<128, 256, 0, stream>>>(nd1, nd2, user[dom], item[dom], labels[dom],
                                        bp, bdu, bdi, acc, dom, B);
    }
    fin_k<<<1, 1, 0, stream>>>(acc, (float*)d_out, B);
}